// Round 19
// baseline (224.849 us; speedup 1.0000x reference)
//
#include <hip/hip_runtime.h>
#include <cstdint>
#include <cstddef>

#define EDIM 256
#define VDIM 8192
#define NPIX 16384
#define QCAP 512

typedef __attribute__((ext_vector_type(8))) short          bf16x8;
typedef __attribute__((ext_vector_type(8))) unsigned short u16x8;
typedef __attribute__((ext_vector_type(4))) float          f32x4;
typedef __attribute__((ext_vector_type(2))) float          f32x2;

// RNE float->bf16
__device__ __forceinline__ unsigned short f2bf(float x) {
    unsigned int u = __float_as_uint(x);
    return (unsigned short)((u + 0x7fffu + ((u >> 16) & 1u)) >> 16);
}

// ---------- numpy pairwise sum-of-squares (exact semantics, verified r2) ----------
__device__ __forceinline__ float np_sqpair128(const float* __restrict__ z) {
    float r[8];
#pragma unroll
    for (int j = 0; j < 8; ++j) r[j] = __fmul_rn(z[j], z[j]);
    for (int i = 8; i < 128; i += 8) {
#pragma unroll
        for (int j = 0; j < 8; ++j)
            r[j] = __fadd_rn(r[j], __fmul_rn(z[i + j], z[i + j]));
    }
    float t01 = __fadd_rn(r[0], r[1]), t23 = __fadd_rn(r[2], r[3]);
    float t45 = __fadd_rn(r[4], r[5]), t67 = __fadd_rn(r[6], r[7]);
    return __fadd_rn(__fadd_rn(t01, t23), __fadd_rn(t45, t67));
}

// ---------------- Stage 1 (FUSED): z32 + zbf frags + A32 + thr (r15/r16-validated) ----------------
__global__ __launch_bounds__(256) void pre_quant_fused(const float* __restrict__ x,
                                                       const float* __restrict__ Wpre,
                                                       const float* __restrict__ bpre,
                                                       float* __restrict__ z32,
                                                       unsigned short* __restrict__ zbf,
                                                       float* __restrict__ A32,
                                                       float* __restrict__ thr) {
#pragma clang fp contract(off)
    __shared__ float xs[32][36];
    __shared__ float wt[32][260];   // [c][e]; aliased as zs[32][260] in epilogue
    int n0 = blockIdx.x * 32;
    int b = n0 >> 8, pix0 = n0 & 255;
    int t = threadIdx.x;
    int ep = t & 31, pg = t >> 5;
    int cc = t >> 3, pp = (t & 7) * 4;   // staging coords

    f32x2 acc[4][4];
#pragma unroll
    for (int pi = 0; pi < 4; ++pi)
#pragma unroll
        for (int j = 0; j < 4; ++j) acc[pi][j] = (f32x2){0.f, 0.f};

    float4 xreg = *(const float4*)&x[(size_t)b * 65536 + (size_t)cc * 256 + pix0 + pp];
    float4 wreg[8];
    {
        const float* wr = Wpre + (size_t)t * 256;
#pragma unroll
        for (int i = 0; i < 8; ++i) wreg[i] = *(const float4*)&wr[i * 4];
    }

    for (int c0 = 0; c0 < 256; c0 += 32) {
        __syncthreads();
        *(float4*)&xs[cc][pp] = xreg;
#pragma unroll
        for (int i = 0; i < 8; ++i) {
            float4 v = wreg[i];
            wt[4 * i + 0][t] = v.x; wt[4 * i + 1][t] = v.y;
            wt[4 * i + 2][t] = v.z; wt[4 * i + 3][t] = v.w;
        }
        __syncthreads();
        if (c0 < 224) {
            int cn = c0 + 32;
            xreg = *(const float4*)&x[(size_t)b * 65536 + (size_t)(cn + cc) * 256 + pix0 + pp];
            const float* wr = Wpre + (size_t)t * 256 + cn;
#pragma unroll
            for (int i = 0; i < 8; ++i) wreg[i] = *(const float4*)&wr[i * 4];
        }
#pragma unroll 8
        for (int c = 0; c < 32; ++c) {
            float4 xv = *(const float4*)&xs[c][pg * 4];
            float xa[4] = {xv.x, xv.y, xv.z, xv.w};
            f32x2 wv[4];
#pragma unroll
            for (int j = 0; j < 4; ++j) wv[j] = *(const f32x2*)&wt[c][2 * ep + 64 * j];
#pragma unroll
            for (int pi = 0; pi < 4; ++pi) {
                f32x2 xsp = {xa[pi], xa[pi]};
#pragma unroll
                for (int j = 0; j < 4; ++j) {
                    f32x2 m = wv[j] * xsp;       // pk_mul (rounded)
                    acc[pi][j] = acc[pi][j] + m;  // pk_add (rounded) — contract off
                }
            }
        }
    }
    __syncthreads();
    float* zs = &wt[0][0];   // [32][260]
    f32x2 b2[4];
#pragma unroll
    for (int j = 0; j < 4; ++j) b2[j] = *(const f32x2*)&bpre[2 * ep + 64 * j];
#pragma unroll
    for (int pi = 0; pi < 4; ++pi) {
        int row = pg * 4 + pi;
#pragma unroll
        for (int j = 0; j < 4; ++j) {
            f32x2 o = acc[pi][j] + b2[j];
            *(f32x2*)&z32[(size_t)(n0 + row) * 256 + 2 * ep + 64 * j] = o;
            *(f32x2*)&zs[row * 260 + 2 * ep + 64 * j] = o;
        }
    }
    __syncthreads();
#pragma unroll
    for (int q = 0; q < 4; ++q) {
        int uid = q * 256 + t;
        int l = uid & 63, ks = (uid >> 6) & 7, tile = uid >> 9;
        int rowl = tile * 16 + (l & 15), colb = ks * 32 + (l >> 4) * 8;
        const float* s = &zs[rowl * 260 + colb];
        float4 a = *(const float4*)s, bb = *(const float4*)(s + 4);
        u16x8 o;
        o[0] = f2bf(a.x); o[1] = f2bf(a.y); o[2] = f2bf(a.z); o[3] = f2bf(a.w);
        o[4] = f2bf(bb.x); o[5] = f2bf(bb.y); o[6] = f2bf(bb.z); o[7] = f2bf(bb.w);
        *((u16x8*)zbf + (((size_t)((n0 >> 4) + tile) * 8 + ks) * 64 + l)) = o;
    }
    if (t < 32) {
        float a = __fadd_rn(np_sqpair128(&zs[t * 260]), np_sqpair128(&zs[t * 260 + 128]));
        A32[n0 + t] = a;
        thr[n0 + t] = 2.75f * sqrtf(a) * 7.0466e-5f - 1e-6f;
    }
}

// ---------------- cb_prep (FUSED): cbf frags + C32 norms + cnt zeroing (r15-validated) ----------------
__global__ __launch_bounds__(256) void cb_prep(const float* __restrict__ cb,
                                               unsigned short* __restrict__ cbf,
                                               float* __restrict__ C32,
                                               int* __restrict__ cnt) {
    int t = threadIdx.x;
    int bid = blockIdx.x;
    int r0 = bid * 32;

    if (t < 64) cnt[bid * 64 + t] = 0;

#pragma unroll
    for (int q = 0; q < 4; ++q) {
        int uid = q * 256 + t;
        int l = uid & 63, ks = (uid >> 6) & 7, tile = uid >> 9;
        int row = r0 + tile * 16 + (l & 15);
        int k = ks * 32 + (l >> 4) * 8;
        const float* s = cb + (size_t)row * 256 + k;
        float4 a = *(const float4*)s, b = *(const float4*)(s + 4);
        u16x8 o;
        o[0] = f2bf(a.x); o[1] = f2bf(a.y); o[2] = f2bf(a.z); o[3] = f2bf(a.w);
        o[4] = f2bf(b.x); o[5] = f2bf(b.y); o[6] = f2bf(b.z); o[7] = f2bf(b.w);
        *((u16x8*)cbf + (((size_t)((r0 >> 4) + tile) * 8 + ks) * 64 + l)) = o;
    }
    {
        int row = r0 + (t >> 3), h = t & 7;
        const float* a = cb + (size_t)row * 256;
        float rA = __fmul_rn(a[h], a[h]);
        float rB = __fmul_rn(a[128 + h], a[128 + h]);
        for (int i = 8; i < 128; i += 8) {
            rA = __fadd_rn(rA, __fmul_rn(a[i + h], a[i + h]));
            rB = __fadd_rn(rB, __fmul_rn(a[128 + i + h], a[128 + i + h]));
        }
        rA = __fadd_rn(rA, __shfl_xor(rA, 1, 8));
        rB = __fadd_rn(rB, __shfl_xor(rB, 1, 8));
        rA = __fadd_rn(rA, __shfl_xor(rA, 2, 8));
        rB = __fadd_rn(rB, __shfl_xor(rB, 2, 8));
        rA = __fadd_rn(rA, __shfl_xor(rA, 4, 8));
        rB = __fadd_rn(rB, __shfl_xor(rB, 4, 8));
        if (h == 0) C32[row] = __fadd_rn(rA, rB);
    }
}

// ---------------- Stage 2: MFMA screen v12 (r14 u32 queue + 5-bit quantized score) ----------------
// r19: entry = rown(14) | qv(5) | v(13). qv = min(31, floor((s-thr)*8/sigma)) — ~4
// VALU on the RARE fire path only; flush = single u32 store (the 92us r14 structure).
// Prune keeps qv >= qmax-3, provably containing the 0.25*sigma exact-winner window.
#define CHECK_TT(A0, A1, A2, A3, TT)                                                \
    do {                                                                            \
        float s0 = __fmaf_rn(-0.5f, cv0, (A0));                                     \
        float s1 = __fmaf_rn(-0.5f, cv1, (A1));                                     \
        float s2 = __fmaf_rn(-0.5f, cv2, (A2));                                     \
        float s3 = __fmaf_rn(-0.5f, cv3, (A3));                                     \
        float mx = fmaxf(fmaxf(s0, s1), fmaxf(s2, s3));                             \
        if (mx > thrv[TT]) {                                                        \
            float ss[4] = {s0, s1, s2, s3};                                         \
            _Pragma("unroll")                                                       \
            for (int j = 0; j < 4; ++j)                                             \
                if (ss[j] > thrv[TT]) {                                             \
                    int slot = atomicAdd(&wq[w], 1);                                \
                    int qv = (int)((ss[j] - thrv[TT]) * qsc[TT]);                   \
                    qv = qv > 31 ? 31 : qv;                                         \
                    unsigned ent = ((unsigned)rown[TT] << 18) |                     \
                                   ((unsigned)qv << 13) | (unsigned)(v0 + j);       \
                    if (slot < QCAP) q[w][slot] = ent;                              \
                    else {                                                          \
                        int sl = atomicAdd(&cnt[rown[TT]], 1);                      \
                        if (sl < 64) cand[(size_t)rown[TT] * 64 + sl] = ent & 0x3FFFFu; \
                    }                                                               \
                }                                                                   \
        }                                                                           \
    } while (0)

#define COMPUTE_TILE(AF, CP, TI)                                                    \
    do {                                                                            \
        f32x4 a0 = {0.f,0.f,0.f,0.f}, a1 = {0.f,0.f,0.f,0.f};                       \
        f32x4 a2 = {0.f,0.f,0.f,0.f}, a3 = {0.f,0.f,0.f,0.f};                       \
        __builtin_amdgcn_s_setprio(1);                                              \
        _Pragma("unroll")                                                           \
        for (int ks = 0; ks < 8; ++ks) {                                            \
            a0 = __builtin_amdgcn_mfma_f32_16x16x32_bf16(AF[ks], zf[0][ks], a0,0,0,0); \
            a1 = __builtin_amdgcn_mfma_f32_16x16x32_bf16(AF[ks], zf[1][ks], a1,0,0,0); \
            a2 = __builtin_amdgcn_mfma_f32_16x16x32_bf16(AF[ks], zf[2][ks], a2,0,0,0); \
            a3 = __builtin_amdgcn_mfma_f32_16x16x32_bf16(AF[ks], zf[3][ks], a3,0,0,0); \
        }                                                                           \
        __builtin_amdgcn_s_setprio(0);                                              \
        int v0 = vblk * 1024 + (TI) * 16 + (l >> 4) * 4;                            \
        float cv0 = CP.x, cv1 = CP.y, cv2 = CP.z, cv3 = CP.w;                       \
        CHECK_TT(a0[0], a0[1], a0[2], a0[3], 0);                                    \
        CHECK_TT(a1[0], a1[1], a1[2], a1[3], 1);                                    \
        CHECK_TT(a2[0], a2[1], a2[2], a2[3], 2);                                    \
        CHECK_TT(a3[0], a3[1], a3[2], a3[3], 3);                                    \
    } while (0)

__global__ __launch_bounds__(512) void screen(const unsigned short* __restrict__ zbf,
                                              const unsigned short* __restrict__ cbf,
                                              const float* __restrict__ C32,
                                              const float* __restrict__ thr,
                                              int* __restrict__ cnt,
                                              unsigned* __restrict__ cand) {
    __shared__ unsigned q[8][QCAP];   // 16 KiB (r14 footprint)
    __shared__ int wq[8];
    int t = threadIdx.x, w = t >> 6, l = t & 63;
    int bid = blockIdx.x;
    int x = bid & 7, k = bid >> 3;
    int rowblk = (x & 3) * 8 + (k & 7);
    int vblk   = (x >> 2) * 4 + (k >> 3);
    int rb = rowblk * 512 + w * 64;

    bf16x8 zf[4][8];
#pragma unroll
    for (int tt = 0; tt < 4; ++tt)
#pragma unroll
        for (int ks = 0; ks < 8; ++ks) {
            zf[tt][ks] = *((const bf16x8*)zbf + (((size_t)((rb >> 4) + tt) * 8 + ks) * 64 + l));
            asm volatile("" : "+a"(zf[tt][ks]));
        }

    int   rown[4];
    float thrv[4], qsc[4];
#pragma unroll
    for (int tt = 0; tt < 4; ++tt) {
        rown[tt] = rb + tt * 16 + (l & 15);
        thrv[tt] = thr[rown[tt]];
        // sigma = (thr + 1e-6)/2.75; qsc = 8/sigma (0.125-sigma quantization steps)
        qsc[tt] = 22.0f / (thrv[tt] + 1e-6f);
    }
    if (t < 8) wq[t] = 0;
    __syncthreads();

    const bf16x8* cb8 = (const bf16x8*)cbf;
    size_t tb = (size_t)(vblk * 64) * 512;
    const float* c32b = C32 + vblk * 1024 + (l >> 4) * 4;

    bf16x8 afA[8], afB[8];
    float4 cpA, cpB;
#pragma unroll
    for (int ks = 0; ks < 8; ++ks)
        afA[ks] = cb8[tb + ks * 64 + l];
    cpA = *(const float4*)&c32b[0];

#pragma unroll 1
    for (int i = 0; i < 64; i += 2) {
        size_t nb = tb + (size_t)(i + 1) * 512;
#pragma unroll
        for (int ks = 0; ks < 8; ++ks)
            afB[ks] = cb8[nb + ks * 64 + l];
        cpB = *(const float4*)&c32b[(i + 1) * 16];
        COMPUTE_TILE(afA, cpA, i);
        if (i < 62) {
            size_t nb2 = tb + (size_t)(i + 2) * 512;
#pragma unroll
            for (int ks = 0; ks < 8; ++ks)
                afA[ks] = cb8[nb2 + ks * 64 + l];
            cpA = *(const float4*)&c32b[(i + 2) * 16];
        }
        COMPUTE_TILE(afB, cpB, i + 1);
    }
    __syncthreads();

    int nq = wq[w] < QCAP ? wq[w] : QCAP;
    for (int i = l; i < nq; i += 64) {
        unsigned ent = q[w][i];
        int row = ent >> 18;
        int sl = atomicAdd(&cnt[row], 1);
        if (sl < 64) cand[(size_t)row * 64 + sl] = ent & 0x3FFFFu;   // (qv<<13)|v
    }
}

// ---------------- Stage 3: re-rank v6 (integer-quantized prune; exact np-f32 chain) ----------------
__global__ __launch_bounds__(256, 3) void rerank(const float* __restrict__ z32,
                                                 const float* __restrict__ cb,
                                                 const float* __restrict__ A32,
                                                 const float* __restrict__ C32,
                                                 const unsigned* __restrict__ cand,
                                                 const int* __restrict__ cnt,
                                                 int* __restrict__ tok_i,
                                                 float* __restrict__ tok_f) {
    __shared__ float    sbuf[32][265];
    __shared__ float    zs[8][264];
    __shared__ unsigned sv[256];
    __shared__ int      svrow[8][32];
    __shared__ int      nc[8];
    __shared__ int      sh[9];
    __shared__ float    dbuf[8][32];
    __shared__ int      vbuf[8][32];
    int t = threadIdx.x;
    int n0 = blockIdx.x * 8;
    int r = t >> 5, l5 = t & 31;

    {
        int e = l5 * 8;
        const float* zr = &z32[(size_t)(n0 + r) * 256 + e];
        *(float4*)&zs[r][e]     = *(const float4*)zr;
        *(float4*)&zs[r][e + 4] = *(const float4*)(zr + 4);
        dbuf[r][l5] = 3.4e38f;
        vbuf[r][l5] = 0x7fffffff;
        if (l5 == 0) nc[r] = 0;
    }
    __syncthreads();

    // phase 1: integer prune — keep qv >= qmax - 3
    {
        int n = cnt[n0 + r]; if (n > 64) n = 64;
        int q1 = -1, q2 = -1, v1 = 0, v2 = 0;
        if (l5 < n) {
            unsigned e1 = cand[(size_t)(n0 + r) * 64 + l5];
            v1 = (int)(e1 & 8191u); q1 = (int)((e1 >> 13) & 31u);
        }
        if (l5 + 32 < n) {
            unsigned e2 = cand[(size_t)(n0 + r) * 64 + l5 + 32];
            v2 = (int)(e2 & 8191u); q2 = (int)((e2 >> 13) & 31u);
        }
        int qm = q1 > q2 ? q1 : q2;
#pragma unroll
        for (int off = 16; off > 0; off >>= 1) {
            int qq = __shfl_xor(qm, off, 32);
            qm = qq > qm ? qq : qm;
        }
        int cut = qm - 3;
        if (q1 >= 0 && q1 >= cut) { int p = atomicAdd(&nc[r], 1); if (p < 32) svrow[r][p] = v1; }
        if (q2 >= 0 && q2 >= cut) { int p = atomicAdd(&nc[r], 1); if (p < 32) svrow[r][p] = v2; }
    }
    __syncthreads();
    if (t == 0) {
        int o = 0;
#pragma unroll
        for (int rr = 0; rr < 8; ++rr) {
            sh[rr] = o;
            int c = nc[rr]; if (c > 32) c = 32;
            o += c;
        }
        sh[8] = o;
    }
    __syncthreads();
    int m = sh[8];
    for (int i = t; i < m; i += 256) {
        int rr = 0;
#pragma unroll
        for (int j = 1; j < 8; ++j) rr += (i >= sh[j]);
        sv[i] = ((unsigned)rr << 13) | (unsigned)svrow[rr][i - sh[rr]];
    }
    __syncthreads();

    // phase 2: exact np-f32 dots for survivors (r14/r16-validated chunked gather + chain)
    {
        bool act = t < m;
        unsigned pk = act ? sv[t] : 0;
        int myrow = pk >> 13, myv = pk & 8191;
        float s = 0.0f;
        int gi = t >> 3, gq = t & 7;

        float4 pf[8];
#pragma unroll
        for (int j = 0; j < 8; ++j) {
            int i = j * 32 + gi;
            if (i < m) pf[j] = *(const float4*)&cb[(size_t)(sv[i] & 8191u) * 256 + gq * 4];
        }
        for (int c = 0; c < 8; ++c) {
            __syncthreads();
#pragma unroll
            for (int j = 0; j < 8; ++j) {
                int i = j * 32 + gi;
                if (i < m) {
                    int kb = gq * 4;
                    sbuf[kb + 0][i] = pf[j].x; sbuf[kb + 1][i] = pf[j].y;
                    sbuf[kb + 2][i] = pf[j].z; sbuf[kb + 3][i] = pf[j].w;
                }
            }
            __syncthreads();
            if (c < 7) {
#pragma unroll
                for (int j = 0; j < 8; ++j) {
                    int i = j * 32 + gi;
                    if (i < m)
                        pf[j] = *(const float4*)&cb[(size_t)(sv[i] & 8191u) * 256 + (c + 1) * 32 + gq * 4];
                }
            }
            if (act) {
                const float* zz = &zs[myrow][c * 32];
#pragma unroll
                for (int k = 0; k < 32; ++k)
                    s = __fmaf_rn(sbuf[k][t], zz[k], s);   // strictly ascending k (r2 chain)
            }
        }
        if (act) {
            float d = __fadd_rn(__fsub_rn(A32[n0 + myrow], __fmul_rn(2.0f, s)), C32[myv]);
            int slot = t - sh[myrow];
            dbuf[myrow][slot] = d;
            vbuf[myrow][slot] = myv;
        }
    }
    __syncthreads();
    {
        float d1 = dbuf[r][l5];
        int   v1 = vbuf[r][l5];
#pragma unroll
        for (int off = 16; off > 0; off >>= 1) {
            float dd = __shfl_xor(d1, off, 32);
            int   vv = __shfl_xor(v1, off, 32);
            if (dd < d1 || (dd == d1 && vv < v1)) { d1 = dd; v1 = vv; }
        }
        if (l5 == 0) { tok_i[n0 + r] = v1; tok_f[n0 + r] = (float)v1; }
    }
}

// ---------------- Stage 4: post_quant v2 (T14 Wpost register-prefetch; r18-validated) ----------------
__global__ __launch_bounds__(256) void post_quant(const float* __restrict__ cb,
                                                  const float* __restrict__ Wpost,
                                                  const float* __restrict__ bpost,
                                                  const int* __restrict__ tok,
                                                  float* __restrict__ rec) {
    __shared__ float zq[256][36];   // [e][pix]
    __shared__ float wt[32][260];   // [e-chunk][cout]
    int n0 = blockIdx.x * 32;
    int b = n0 >> 8, pix0 = n0 & 255;
    int t = threadIdx.x;
    int ep = t & 31, pg = t >> 5;

    {   int pix = t & 31, eg = t >> 5;
        int tv = tok[n0 + pix];
        const float* cr = cb + (size_t)tv * 256 + eg * 32;
#pragma unroll
        for (int i = 0; i < 32; ++i)
            zq[eg * 32 + i][pix] = cr[i];
    }

    float4 wreg[8];
    {
        const float* wr = Wpost + (size_t)t * 256;
#pragma unroll
        for (int i = 0; i < 8; ++i) wreg[i] = *(const float4*)&wr[i * 4];
    }

    f32x2 acc[8][2];
#pragma unroll
    for (int s = 0; s < 8; ++s) { acc[s][0] = (f32x2){0.f, 0.f}; acc[s][1] = (f32x2){0.f, 0.f}; }

    for (int e0 = 0; e0 < 256; e0 += 32) {
        __syncthreads();
#pragma unroll
        for (int i = 0; i < 8; ++i) {
            float4 v = wreg[i];
            wt[4 * i + 0][t] = v.x; wt[4 * i + 1][t] = v.y;
            wt[4 * i + 2][t] = v.z; wt[4 * i + 3][t] = v.w;
        }
        __syncthreads();
        if (e0 < 224) {
            const float* wr = Wpost + (size_t)t * 256 + e0 + 32;
#pragma unroll
            for (int i = 0; i < 8; ++i) wreg[i] = *(const float4*)&wr[i * 4];
        }
#pragma unroll 8
        for (int ee = 0; ee < 32; ++ee) {
            float4 zv = *(const float4*)&zq[e0 + ee][pg * 4];
            f32x2 zp0 = {zv.x, zv.y}, zp1 = {zv.z, zv.w};
#pragma unroll
            for (int J = 0; J < 4; ++J) {
                f32x2 wv = *(const f32x2*)&wt[ee][2 * ep + 64 * J];
                f32x2 w0 = {wv[0], wv[0]}, w1 = {wv[1], wv[1]};
                acc[2 * J + 0][0] = w0 * zp0 + acc[2 * J + 0][0];
                acc[2 * J + 0][1] = w0 * zp1 + acc[2 * J + 0][1];
                acc[2 * J + 1][0] = w1 * zp0 + acc[2 * J + 1][0];
                acc[2 * J + 1][1] = w1 * zp1 + acc[2 * J + 1][1];
            }
        }
    }
#pragma unroll
    for (int J = 0; J < 4; ++J)
#pragma unroll
        for (int c01 = 0; c01 < 2; ++c01) {
            int cout = 2 * ep + 64 * J + c01;
            float bv = bpost[cout];
            f32x2 bs = {bv, bv};
            f32x2 o0 = acc[2 * J + c01][0] + bs, o1 = acc[2 * J + c01][1] + bs;
            float4 ov = {o0[0], o0[1], o1[0], o1[1]};
            *(float4*)&rec[(size_t)b * 65536 + (size_t)cout * 256 + pix0 + pg * 4] = ov;
        }
}

// ---------------- Launch ----------------
extern "C" void kernel_launch(void* const* d_in, const int* in_sizes, int n_in,
                              void* d_out, int out_size, void* d_ws, size_t ws_size,
                              hipStream_t stream) {
    const float* x     = (const float*)d_in[0];
    const float* Wpre  = (const float*)d_in[1];
    const float* bpre  = (const float*)d_in[2];
    const float* cb    = (const float*)d_in[3];
    const float* Wpost = (const float*)d_in[4];
    const float* bpost = (const float*)d_in[5];

    float* out   = (float*)d_out;
    float* rec   = out;
    float* tok_f = out + 4194304;
    float* z32   = rec;   // z lives in rec region until post_quant overwrites it

    char* ws = (char*)d_ws;
    float*          A32   = (float*)(ws + 0);          // 64 KiB
    float*          C32   = (float*)(ws + 65536);      // 32 KiB
    int*            tok_i = (int*)(ws + 98304);        // 64 KiB
    float*          thr   = (float*)(ws + 163840);     // 64 KiB
    int*            cnt   = (int*)(ws + 229376);       // 64 KiB
    unsigned*       cand  = (unsigned*)(ws + 294912);  // 4 MiB
    unsigned short* zbf   = (unsigned short*)(ws + 4489216);   // 8 MiB
    unsigned short* cbf   = (unsigned short*)(ws + 12877824);  // 4 MiB

    pre_quant_fused<<<NPIX / 32, 256, 0, stream>>>(x, Wpre, bpre, z32, zbf, A32, thr);
    cb_prep<<<VDIM / 32, 256, 0, stream>>>(cb, cbf, C32, cnt);
    screen<<<256, 512, 0, stream>>>(zbf, cbf, C32, thr, cnt, cand);
    rerank<<<NPIX / 8, 256, 0, stream>>>(z32, cb, A32, C32, cand, cnt, tok_i, tok_f);
    post_quant<<<NPIX / 32, 256, 0, stream>>>(cb, Wpost, bpost, tok_i, rec);
}

// Round 20
// 212.902 us; speedup vs baseline: 1.0561x; 1.0561x over previous
//
#include <hip/hip_runtime.h>
#include <cstdint>
#include <cstddef>

#define EDIM 256
#define VDIM 8192
#define NPIX 16384
#define QCAP 512

typedef __attribute__((ext_vector_type(8))) short          bf16x8;
typedef __attribute__((ext_vector_type(8))) unsigned short u16x8;
typedef __attribute__((ext_vector_type(4))) float          f32x4;
typedef __attribute__((ext_vector_type(2))) float          f32x2;

// RNE float->bf16
__device__ __forceinline__ unsigned short f2bf(float x) {
    unsigned int u = __float_as_uint(x);
    return (unsigned short)((u + 0x7fffu + ((u >> 16) & 1u)) >> 16);
}

// ---------- numpy pairwise sum-of-squares (exact semantics, verified r2) ----------
__device__ __forceinline__ float np_sqpair128(const float* __restrict__ z) {
    float r[8];
#pragma unroll
    for (int j = 0; j < 8; ++j) r[j] = __fmul_rn(z[j], z[j]);
    for (int i = 8; i < 128; i += 8) {
#pragma unroll
        for (int j = 0; j < 8; ++j)
            r[j] = __fadd_rn(r[j], __fmul_rn(z[i + j], z[i + j]));
    }
    float t01 = __fadd_rn(r[0], r[1]), t23 = __fadd_rn(r[2], r[3]);
    float t45 = __fadd_rn(r[4], r[5]), t67 = __fadd_rn(r[6], r[7]);
    return __fadd_rn(__fadd_rn(t01, t23), __fadd_rn(t45, t67));
}

// ---------------- Stage 1 (FUSED): z32 + zbf frags + A32 + thr (r15/r16-validated) ----------------
__global__ __launch_bounds__(256) void pre_quant_fused(const float* __restrict__ x,
                                                       const float* __restrict__ Wpre,
                                                       const float* __restrict__ bpre,
                                                       float* __restrict__ z32,
                                                       unsigned short* __restrict__ zbf,
                                                       float* __restrict__ A32,
                                                       float* __restrict__ thr) {
#pragma clang fp contract(off)
    __shared__ float xs[32][36];
    __shared__ float wt[32][260];   // [c][e]; aliased as zs[32][260] in epilogue
    int n0 = blockIdx.x * 32;
    int b = n0 >> 8, pix0 = n0 & 255;
    int t = threadIdx.x;
    int ep = t & 31, pg = t >> 5;
    int cc = t >> 3, pp = (t & 7) * 4;   // staging coords

    f32x2 acc[4][4];
#pragma unroll
    for (int pi = 0; pi < 4; ++pi)
#pragma unroll
        for (int j = 0; j < 4; ++j) acc[pi][j] = (f32x2){0.f, 0.f};

    float4 xreg = *(const float4*)&x[(size_t)b * 65536 + (size_t)cc * 256 + pix0 + pp];
    float4 wreg[8];
    {
        const float* wr = Wpre + (size_t)t * 256;
#pragma unroll
        for (int i = 0; i < 8; ++i) wreg[i] = *(const float4*)&wr[i * 4];
    }

    for (int c0 = 0; c0 < 256; c0 += 32) {
        __syncthreads();
        *(float4*)&xs[cc][pp] = xreg;
#pragma unroll
        for (int i = 0; i < 8; ++i) {
            float4 v = wreg[i];
            wt[4 * i + 0][t] = v.x; wt[4 * i + 1][t] = v.y;
            wt[4 * i + 2][t] = v.z; wt[4 * i + 3][t] = v.w;
        }
        __syncthreads();
        if (c0 < 224) {
            int cn = c0 + 32;
            xreg = *(const float4*)&x[(size_t)b * 65536 + (size_t)(cn + cc) * 256 + pix0 + pp];
            const float* wr = Wpre + (size_t)t * 256 + cn;
#pragma unroll
            for (int i = 0; i < 8; ++i) wreg[i] = *(const float4*)&wr[i * 4];
        }
#pragma unroll 8
        for (int c = 0; c < 32; ++c) {
            float4 xv = *(const float4*)&xs[c][pg * 4];
            float xa[4] = {xv.x, xv.y, xv.z, xv.w};
            f32x2 wv[4];
#pragma unroll
            for (int j = 0; j < 4; ++j) wv[j] = *(const f32x2*)&wt[c][2 * ep + 64 * j];
#pragma unroll
            for (int pi = 0; pi < 4; ++pi) {
                f32x2 xsp = {xa[pi], xa[pi]};
#pragma unroll
                for (int j = 0; j < 4; ++j) {
                    f32x2 m = wv[j] * xsp;       // pk_mul (rounded)
                    acc[pi][j] = acc[pi][j] + m;  // pk_add (rounded) — contract off
                }
            }
        }
    }
    __syncthreads();
    float* zs = &wt[0][0];   // [32][260]
    f32x2 b2[4];
#pragma unroll
    for (int j = 0; j < 4; ++j) b2[j] = *(const f32x2*)&bpre[2 * ep + 64 * j];
#pragma unroll
    for (int pi = 0; pi < 4; ++pi) {
        int row = pg * 4 + pi;
#pragma unroll
        for (int j = 0; j < 4; ++j) {
            f32x2 o = acc[pi][j] + b2[j];
            *(f32x2*)&z32[(size_t)(n0 + row) * 256 + 2 * ep + 64 * j] = o;
            *(f32x2*)&zs[row * 260 + 2 * ep + 64 * j] = o;
        }
    }
    __syncthreads();
#pragma unroll
    for (int q = 0; q < 4; ++q) {
        int uid = q * 256 + t;
        int l = uid & 63, ks = (uid >> 6) & 7, tile = uid >> 9;
        int rowl = tile * 16 + (l & 15), colb = ks * 32 + (l >> 4) * 8;
        const float* s = &zs[rowl * 260 + colb];
        float4 a = *(const float4*)s, bb = *(const float4*)(s + 4);
        u16x8 o;
        o[0] = f2bf(a.x); o[1] = f2bf(a.y); o[2] = f2bf(a.z); o[3] = f2bf(a.w);
        o[4] = f2bf(bb.x); o[5] = f2bf(bb.y); o[6] = f2bf(bb.z); o[7] = f2bf(bb.w);
        *((u16x8*)zbf + (((size_t)((n0 >> 4) + tile) * 8 + ks) * 64 + l)) = o;
    }
    if (t < 32) {
        float a = __fadd_rn(np_sqpair128(&zs[t * 260]), np_sqpair128(&zs[t * 260 + 128]));
        A32[n0 + t] = a;
        thr[n0 + t] = 2.75f * sqrtf(a) * 7.0466e-5f - 1e-6f;
    }
}

// ---------------- cb_prep (FUSED): cbf frags + C32 norms + cnt zeroing (r15-validated) ----------------
__global__ __launch_bounds__(256) void cb_prep(const float* __restrict__ cb,
                                               unsigned short* __restrict__ cbf,
                                               float* __restrict__ C32,
                                               int* __restrict__ cnt) {
    int t = threadIdx.x;
    int bid = blockIdx.x;
    int r0 = bid * 32;

    if (t < 64) cnt[bid * 64 + t] = 0;

#pragma unroll
    for (int q = 0; q < 4; ++q) {
        int uid = q * 256 + t;
        int l = uid & 63, ks = (uid >> 6) & 7, tile = uid >> 9;
        int row = r0 + tile * 16 + (l & 15);
        int k = ks * 32 + (l >> 4) * 8;
        const float* s = cb + (size_t)row * 256 + k;
        float4 a = *(const float4*)s, b = *(const float4*)(s + 4);
        u16x8 o;
        o[0] = f2bf(a.x); o[1] = f2bf(a.y); o[2] = f2bf(a.z); o[3] = f2bf(a.w);
        o[4] = f2bf(b.x); o[5] = f2bf(b.y); o[6] = f2bf(b.z); o[7] = f2bf(b.w);
        *((u16x8*)cbf + (((size_t)((r0 >> 4) + tile) * 8 + ks) * 64 + l)) = o;
    }
    {
        int row = r0 + (t >> 3), h = t & 7;
        const float* a = cb + (size_t)row * 256;
        float rA = __fmul_rn(a[h], a[h]);
        float rB = __fmul_rn(a[128 + h], a[128 + h]);
        for (int i = 8; i < 128; i += 8) {
            rA = __fadd_rn(rA, __fmul_rn(a[i + h], a[i + h]));
            rB = __fadd_rn(rB, __fmul_rn(a[128 + i + h], a[128 + i + h]));
        }
        rA = __fadd_rn(rA, __shfl_xor(rA, 1, 8));
        rB = __fadd_rn(rB, __shfl_xor(rB, 1, 8));
        rA = __fadd_rn(rA, __shfl_xor(rA, 2, 8));
        rB = __fadd_rn(rB, __shfl_xor(rB, 2, 8));
        rA = __fadd_rn(rA, __shfl_xor(rA, 4, 8));
        rB = __fadd_rn(rB, __shfl_xor(rB, 4, 8));
        if (h == 0) C32[row] = __fadd_rn(rA, rB);
    }
}

// ---------------- Stage 2: MFMA screen v10 (exact r16 source — measured 100us whole-config) ----------------
#define CHECK_TT(A0, A1, A2, A3, TT)                                                \
    do {                                                                            \
        float s0 = __fmaf_rn(-0.5f, cv0, (A0));                                     \
        float s1 = __fmaf_rn(-0.5f, cv1, (A1));                                     \
        float s2 = __fmaf_rn(-0.5f, cv2, (A2));                                     \
        float s3 = __fmaf_rn(-0.5f, cv3, (A3));                                     \
        float mx = fmaxf(fmaxf(s0, s1), fmaxf(s2, s3));                             \
        if (mx > thrv[TT]) {                                                        \
            float ss[4] = {s0, s1, s2, s3};                                         \
            _Pragma("unroll")                                                       \
            for (int j = 0; j < 4; ++j)                                             \
                if (ss[j] > thrv[TT]) {                                             \
                    int slot = atomicAdd(&wq[w], 1);                                \
                    unsigned pk = ((unsigned)rown[TT] << 13) | (unsigned)(v0 + j);  \
                    if (slot < QCAP) { q[w][slot] = pk; qs[w][slot] = ss[j]; }      \
                    else {                                                          \
                        int sl = atomicAdd(&cnt[rown[TT]], 1);                      \
                        if (sl < 64) {                                              \
                            cand[(size_t)rown[TT] * 64 + sl] = v0 + j;              \
                            scr[(size_t)rown[TT] * 64 + sl] = ss[j];                \
                        }                                                           \
                    }                                                               \
                }                                                                   \
        }                                                                           \
    } while (0)

#define COMPUTE_TILE(AF, CP, TI)                                                    \
    do {                                                                            \
        f32x4 a0 = {0.f,0.f,0.f,0.f}, a1 = {0.f,0.f,0.f,0.f};                       \
        f32x4 a2 = {0.f,0.f,0.f,0.f}, a3 = {0.f,0.f,0.f,0.f};                       \
        __builtin_amdgcn_s_setprio(1);                                              \
        _Pragma("unroll")                                                           \
        for (int ks = 0; ks < 8; ++ks) {                                            \
            a0 = __builtin_amdgcn_mfma_f32_16x16x32_bf16(AF[ks], zf[0][ks], a0,0,0,0); \
            a1 = __builtin_amdgcn_mfma_f32_16x16x32_bf16(AF[ks], zf[1][ks], a1,0,0,0); \
            a2 = __builtin_amdgcn_mfma_f32_16x16x32_bf16(AF[ks], zf[2][ks], a2,0,0,0); \
            a3 = __builtin_amdgcn_mfma_f32_16x16x32_bf16(AF[ks], zf[3][ks], a3,0,0,0); \
        }                                                                           \
        __builtin_amdgcn_s_setprio(0);                                              \
        int v0 = vblk * 1024 + (TI) * 16 + (l >> 4) * 4;                            \
        float cv0 = CP.x, cv1 = CP.y, cv2 = CP.z, cv3 = CP.w;                       \
        CHECK_TT(a0[0], a0[1], a0[2], a0[3], 0);                                    \
        CHECK_TT(a1[0], a1[1], a1[2], a1[3], 1);                                    \
        CHECK_TT(a2[0], a2[1], a2[2], a2[3], 2);                                    \
        CHECK_TT(a3[0], a3[1], a3[2], a3[3], 3);                                    \
    } while (0)

__global__ __launch_bounds__(512) void screen(const unsigned short* __restrict__ zbf,
                                              const unsigned short* __restrict__ cbf,
                                              const float* __restrict__ C32,
                                              const float* __restrict__ thr,
                                              int* __restrict__ cnt,
                                              int* __restrict__ cand,
                                              float* __restrict__ scr) {
    __shared__ unsigned q[8][QCAP];    // 16 KiB
    __shared__ float    qs[8][QCAP];   // 16 KiB scores
    __shared__ int wq[8];
    int t = threadIdx.x, w = t >> 6, l = t & 63;
    int bid = blockIdx.x;
    int x = bid & 7, k = bid >> 3;
    int rowblk = (x & 3) * 8 + (k & 7);
    int vblk   = (x >> 2) * 4 + (k >> 3);
    int rb = rowblk * 512 + w * 64;

    bf16x8 zf[4][8];
#pragma unroll
    for (int tt = 0; tt < 4; ++tt)
#pragma unroll
        for (int ks = 0; ks < 8; ++ks) {
            zf[tt][ks] = *((const bf16x8*)zbf + (((size_t)((rb >> 4) + tt) * 8 + ks) * 64 + l));
            asm volatile("" : "+a"(zf[tt][ks]));
        }

    int   rown[4];
    float thrv[4];
#pragma unroll
    for (int tt = 0; tt < 4; ++tt) {
        rown[tt] = rb + tt * 16 + (l & 15);
        thrv[tt] = thr[rown[tt]];
    }
    if (t < 8) wq[t] = 0;
    __syncthreads();

    const bf16x8* cb8 = (const bf16x8*)cbf;
    size_t tb = (size_t)(vblk * 64) * 512;
    const float* c32b = C32 + vblk * 1024 + (l >> 4) * 4;

    bf16x8 afA[8], afB[8];
    float4 cpA, cpB;
#pragma unroll
    for (int ks = 0; ks < 8; ++ks)
        afA[ks] = cb8[tb + ks * 64 + l];
    cpA = *(const float4*)&c32b[0];

#pragma unroll 1
    for (int i = 0; i < 64; i += 2) {
        size_t nb = tb + (size_t)(i + 1) * 512;
#pragma unroll
        for (int ks = 0; ks < 8; ++ks)
            afB[ks] = cb8[nb + ks * 64 + l];
        cpB = *(const float4*)&c32b[(i + 1) * 16];
        COMPUTE_TILE(afA, cpA, i);
        if (i < 62) {
            size_t nb2 = tb + (size_t)(i + 2) * 512;
#pragma unroll
            for (int ks = 0; ks < 8; ++ks)
                afA[ks] = cb8[nb2 + ks * 64 + l];
            cpA = *(const float4*)&c32b[(i + 2) * 16];
        }
        COMPUTE_TILE(afB, cpB, i + 1);
    }
    __syncthreads();

    int nq = wq[w] < QCAP ? wq[w] : QCAP;
    for (int i = l; i < nq; i += 64) {
        unsigned pk = q[w][i];
        int row = pk >> 13, v = pk & 8191;
        int sl = atomicAdd(&cnt[row], 1);
        if (sl < 64) {
            cand[(size_t)row * 64 + sl] = v;
            scr[(size_t)row * 64 + sl] = qs[w][i];
        }
    }
}

// ---------------- Stage 3: re-rank v4 (exact r16 source) ----------------
__global__ __launch_bounds__(256, 3) void rerank(const float* __restrict__ z32,
                                                 const float* __restrict__ cb,
                                                 const float* __restrict__ A32,
                                                 const float* __restrict__ C32,
                                                 const int* __restrict__ cand,
                                                 const float* __restrict__ scr,
                                                 const int* __restrict__ cnt,
                                                 int* __restrict__ tok_i,
                                                 float* __restrict__ tok_f) {
    __shared__ float    sbuf[32][265];
    __shared__ float    zs[8][264];
    __shared__ unsigned sv[256];
    __shared__ int      svrow[8][32];
    __shared__ int      nc[8];
    __shared__ int      sh[9];
    __shared__ float    dbuf[8][32];
    __shared__ int      vbuf[8][32];
    int t = threadIdx.x;
    int n0 = blockIdx.x * 8;
    int r = t >> 5, l5 = t & 31;

    {
        int e = l5 * 8;
        const float* zr = &z32[(size_t)(n0 + r) * 256 + e];
        *(float4*)&zs[r][e]     = *(const float4*)zr;
        *(float4*)&zs[r][e + 4] = *(const float4*)(zr + 4);
        dbuf[r][l5] = 3.4e38f;
        vbuf[r][l5] = 0x7fffffff;
        if (l5 == 0) nc[r] = 0;
    }
    __syncthreads();

    {
        int n = cnt[n0 + r]; if (n > 64) n = 64;
        int cv1 = -1, cv2 = -1; float s1 = -3.4e38f, s2 = -3.4e38f;
        if (l5 < n)      { cv1 = cand[(size_t)(n0 + r) * 64 + l5];      s1 = scr[(size_t)(n0 + r) * 64 + l5]; }
        if (l5 + 32 < n) { cv2 = cand[(size_t)(n0 + r) * 64 + l5 + 32]; s2 = scr[(size_t)(n0 + r) * 64 + l5 + 32]; }
        float smax = fmaxf(s1, s2);
#pragma unroll
        for (int off = 16; off > 0; off >>= 1)
            smax = fmaxf(smax, __shfl_xor(smax, off, 32));
        float sig = sqrtf(A32[n0 + r]) * 7.0466e-5f;
        float cut = smax - __fmaf_rn(0.25f, sig, 1e-4f);
        if (cv1 >= 0 && s1 >= cut) { int p = atomicAdd(&nc[r], 1); if (p < 32) svrow[r][p] = cv1; }
        if (cv2 >= 0 && s2 >= cut) { int p = atomicAdd(&nc[r], 1); if (p < 32) svrow[r][p] = cv2; }
    }
    __syncthreads();
    if (t == 0) {
        int o = 0;
#pragma unroll
        for (int rr = 0; rr < 8; ++rr) {
            sh[rr] = o;
            int c = nc[rr]; if (c > 32) c = 32;
            o += c;
        }
        sh[8] = o;
    }
    __syncthreads();
    int m = sh[8];
    for (int i = t; i < m; i += 256) {
        int rr = 0;
#pragma unroll
        for (int j = 1; j < 8; ++j) rr += (i >= sh[j]);
        sv[i] = ((unsigned)rr << 13) | (unsigned)svrow[rr][i - sh[rr]];
    }
    __syncthreads();

    {
        bool act = t < m;
        unsigned pk = act ? sv[t] : 0;
        int myrow = pk >> 13, myv = pk & 8191;
        float s = 0.0f;
        int gi = t >> 3, gq = t & 7;

        float4 pf[8];
#pragma unroll
        for (int j = 0; j < 8; ++j) {
            int i = j * 32 + gi;
            if (i < m) pf[j] = *(const float4*)&cb[(size_t)(sv[i] & 8191u) * 256 + gq * 4];
        }
        for (int c = 0; c < 8; ++c) {
            __syncthreads();
#pragma unroll
            for (int j = 0; j < 8; ++j) {
                int i = j * 32 + gi;
                if (i < m) {
                    int kb = gq * 4;
                    sbuf[kb + 0][i] = pf[j].x; sbuf[kb + 1][i] = pf[j].y;
                    sbuf[kb + 2][i] = pf[j].z; sbuf[kb + 3][i] = pf[j].w;
                }
            }
            __syncthreads();
            if (c < 7) {
#pragma unroll
                for (int j = 0; j < 8; ++j) {
                    int i = j * 32 + gi;
                    if (i < m)
                        pf[j] = *(const float4*)&cb[(size_t)(sv[i] & 8191u) * 256 + (c + 1) * 32 + gq * 4];
                }
            }
            if (act) {
                const float* zz = &zs[myrow][c * 32];
#pragma unroll
                for (int k = 0; k < 32; ++k)
                    s = __fmaf_rn(sbuf[k][t], zz[k], s);   // strictly ascending k (r2 chain)
            }
        }
        if (act) {
            float d = __fadd_rn(__fsub_rn(A32[n0 + myrow], __fmul_rn(2.0f, s)), C32[myv]);
            int slot = t - sh[myrow];
            dbuf[myrow][slot] = d;
            vbuf[myrow][slot] = myv;
        }
    }
    __syncthreads();
    {
        float d1 = dbuf[r][l5];
        int   v1 = vbuf[r][l5];
#pragma unroll
        for (int off = 16; off > 0; off >>= 1) {
            float dd = __shfl_xor(d1, off, 32);
            int   vv = __shfl_xor(v1, off, 32);
            if (dd < d1 || (dd == d1 && vv < v1)) { d1 = dd; v1 = vv; }
        }
        if (l5 == 0) { tok_i[n0 + r] = v1; tok_f[n0 + r] = (float)v1; }
    }
}

// ---------------- Stage 4: post_quant v2 (T14 Wpost register-prefetch; r18/r19-validated) ----------------
__global__ __launch_bounds__(256) void post_quant(const float* __restrict__ cb,
                                                  const float* __restrict__ Wpost,
                                                  const float* __restrict__ bpost,
                                                  const int* __restrict__ tok,
                                                  float* __restrict__ rec) {
    __shared__ float zq[256][36];   // [e][pix]
    __shared__ float wt[32][260];   // [e-chunk][cout]
    int n0 = blockIdx.x * 32;
    int b = n0 >> 8, pix0 = n0 & 255;
    int t = threadIdx.x;
    int ep = t & 31, pg = t >> 5;

    {   int pix = t & 31, eg = t >> 5;
        int tv = tok[n0 + pix];
        const float* cr = cb + (size_t)tv * 256 + eg * 32;
#pragma unroll
        for (int i = 0; i < 32; ++i)
            zq[eg * 32 + i][pix] = cr[i];
    }

    float4 wreg[8];
    {
        const float* wr = Wpost + (size_t)t * 256;
#pragma unroll
        for (int i = 0; i < 8; ++i) wreg[i] = *(const float4*)&wr[i * 4];
    }

    f32x2 acc[8][2];
#pragma unroll
    for (int s = 0; s < 8; ++s) { acc[s][0] = (f32x2){0.f, 0.f}; acc[s][1] = (f32x2){0.f, 0.f}; }

    for (int e0 = 0; e0 < 256; e0 += 32) {
        __syncthreads();
#pragma unroll
        for (int i = 0; i < 8; ++i) {
            float4 v = wreg[i];
            wt[4 * i + 0][t] = v.x; wt[4 * i + 1][t] = v.y;
            wt[4 * i + 2][t] = v.z; wt[4 * i + 3][t] = v.w;
        }
        __syncthreads();
        if (e0 < 224) {
            const float* wr = Wpost + (size_t)t * 256 + e0 + 32;
#pragma unroll
            for (int i = 0; i < 8; ++i) wreg[i] = *(const float4*)&wr[i * 4];
        }
#pragma unroll 8
        for (int ee = 0; ee < 32; ++ee) {
            float4 zv = *(const float4*)&zq[e0 + ee][pg * 4];
            f32x2 zp0 = {zv.x, zv.y}, zp1 = {zv.z, zv.w};
#pragma unroll
            for (int J = 0; J < 4; ++J) {
                f32x2 wv = *(const f32x2*)&wt[ee][2 * ep + 64 * J];
                f32x2 w0 = {wv[0], wv[0]}, w1 = {wv[1], wv[1]};
                acc[2 * J + 0][0] = w0 * zp0 + acc[2 * J + 0][0];
                acc[2 * J + 0][1] = w0 * zp1 + acc[2 * J + 0][1];
                acc[2 * J + 1][0] = w1 * zp0 + acc[2 * J + 1][0];
                acc[2 * J + 1][1] = w1 * zp1 + acc[2 * J + 1][1];
            }
        }
    }
#pragma unroll
    for (int J = 0; J < 4; ++J)
#pragma unroll
        for (int c01 = 0; c01 < 2; ++c01) {
            int cout = 2 * ep + 64 * J + c01;
            float bv = bpost[cout];
            f32x2 bs = {bv, bv};
            f32x2 o0 = acc[2 * J + c01][0] + bs, o1 = acc[2 * J + c01][1] + bs;
            float4 ov = {o0[0], o0[1], o1[0], o1[1]};
            *(float4*)&rec[(size_t)b * 65536 + (size_t)cout * 256 + pix0 + pg * 4] = ov;
        }
}

// ---------------- Launch ----------------
extern "C" void kernel_launch(void* const* d_in, const int* in_sizes, int n_in,
                              void* d_out, int out_size, void* d_ws, size_t ws_size,
                              hipStream_t stream) {
    const float* x     = (const float*)d_in[0];
    const float* Wpre  = (const float*)d_in[1];
    const float* bpre  = (const float*)d_in[2];
    const float* cb    = (const float*)d_in[3];
    const float* Wpost = (const float*)d_in[4];
    const float* bpost = (const float*)d_in[5];

    float* out   = (float*)d_out;
    float* rec   = out;
    float* tok_f = out + 4194304;
    float* z32   = rec;   // z lives in rec region until post_quant overwrites it

    char* ws = (char*)d_ws;
    float*          A32   = (float*)(ws + 0);          // 64 KiB
    float*          C32   = (float*)(ws + 65536);      // 32 KiB
    int*            tok_i = (int*)(ws + 98304);        // 64 KiB
    float*          thr   = (float*)(ws + 163840);     // 64 KiB
    int*            cnt   = (int*)(ws + 229376);       // 64 KiB
    int*            cand  = (int*)(ws + 294912);       // 4 MiB
    unsigned short* zbf   = (unsigned short*)(ws + 4489216);   // 8 MiB
    unsigned short* cbf   = (unsigned short*)(ws + 12877824);  // 4 MiB
    float*          scr   = (float*)(ws + 17072128);   // 4 MiB

    pre_quant_fused<<<NPIX / 32, 256, 0, stream>>>(x, Wpre, bpre, z32, zbf, A32, thr);
    cb_prep<<<VDIM / 32, 256, 0, stream>>>(cb, cbf, C32, cnt);
    screen<<<256, 512, 0, stream>>>(zbf, cbf, C32, thr, cnt, cand, scr);
    rerank<<<NPIX / 8, 256, 0, stream>>>(z32, cb, A32, C32, cand, scr, cnt, tok_i, tok_f);
    post_quant<<<NPIX / 32, 256, 0, stream>>>(cb, Wpost, bpost, tok_i, rec);
}